// Round 1
// baseline (90.313 us; speedup 1.0000x reference)
//
#include <hip/hip_runtime.h>
#include <stdint.h>

#define N_ATOMS 8192
#define KNB 32            // MAX_NEIGHBORS
#define CUTOFF_F 5.0f
#define SORT_N 256        // >= max molecule size (Binomial(8192,1/64): mean 128, 6sigma ~ 196)

// One block per atom. batch is sorted -> molecule = contiguous range found by
// binary search. Bitonic sort of packed (dist_bits<<32 | j) keys gives the K
// nearest in ascending-distance order with ties broken by lower index,
// matching jax.lax.top_k(-masked_dist, K).
__global__ __launch_bounds__(SORT_N) void radius_graph_kernel(
    const float* __restrict__ pos, const int* __restrict__ batch,
    float* __restrict__ out)
{
    const int i   = blockIdx.x;
    const int tid = threadIdx.x;
    __shared__ uint64_t keys[SORT_N];

    const int b = batch[i];

    // lower bound: first idx with batch[idx] >= b  (uniform across block)
    int lo = 0, hi = N_ATOMS;
    while (lo < hi) { int mid = (lo + hi) >> 1; if (batch[mid] < b) lo = mid + 1; else hi = mid; }
    const int start = lo;
    // upper bound: first idx with batch[idx] > b
    lo = 0; hi = N_ATOMS;
    while (lo < hi) { int mid = (lo + hi) >> 1; if (batch[mid] <= b) lo = mid + 1; else hi = mid; }
    const int end = lo;   // molecule = [start, end); end-start <= SORT_N for this data

    const float xi = pos[3 * i], yi = pos[3 * i + 1], zi = pos[3 * i + 2];
    const float sqi = xi * xi + yi * yi + zi * zi;

    uint64_t key = ~0ULL;   // invalid sentinel sorts last
    const int j = start + tid;
    if (j < end && j != i) {
        const float xj = pos[3 * j], yj = pos[3 * j + 1], zj = pos[3 * j + 2];
        const float sqj = xj * xj + yj * yj + zj * zj;
        const float dot = xi * xj + yi * yj + zi * zj;
        const float d2  = (sqi + sqj) - 2.0f * dot;          // reference's gram trick
        const float dist = sqrtf(fmaxf(d2, 0.0f));
        if (dist <= CUTOFF_F) {
            const uint32_t fb = __float_as_uint(dist);        // dist >= 0: bits order = float order
            key = ((uint64_t)fb << 32) | (uint32_t)j;
        }
    }
    keys[tid] = key;
    __syncthreads();

    // Bitonic sort, ascending. Each (tid, tid^jj) pair handled by the lower tid.
    for (int k = 2; k <= SORT_N; k <<= 1) {
        for (int jj = k >> 1; jj > 0; jj >>= 1) {
            const int ixj = tid ^ jj;
            if (ixj > tid) {
                const uint64_t a = keys[tid], c = keys[ixj];
                const bool up = ((tid & k) == 0);
                if ((a > c) == up) { keys[tid] = c; keys[ixj] = a; }
            }
            __syncthreads();
        }
    }

    if (tid < KNB) {
        const uint64_t kk   = keys[tid];
        const bool   valid  = (kk != ~0ULL);
        const int    dst    = valid ? (int)(uint32_t)(kk & 0xFFFFFFFFu) : i;
        const long long NK  = (long long)N_ATOMS * KNB;
        const long long e   = (long long)i * KNB + tid;

        out[e]      = (float)i;     // edge_index row 0: src
        out[NK + e] = (float)dst;   // edge_index row 1: dst (pad -> self)

        float vx = 0.0f, vy = 0.0f, vz = 0.0f;
        if (valid) {
            vx = pos[3 * dst]     - xi;
            vy = pos[3 * dst + 1] - yi;
            vz = pos[3 * dst + 2] - zi;
        }
        out[2 * NK + 3 * e]     = vx;
        out[2 * NK + 3 * e + 1] = vy;
        out[2 * NK + 3 * e + 2] = vz;

        out[5 * NK + e] = valid ? 1.0f : 0.0f;  // edge_mask
    }
}

extern "C" void kernel_launch(void* const* d_in, const int* in_sizes, int n_in,
                              void* d_out, int out_size, void* d_ws, size_t ws_size,
                              hipStream_t stream) {
    const float* pos   = (const float*)d_in[0];   // [8192, 3] f32
    const int*   batch = (const int*)d_in[1];     // [8192] i32, sorted
    float*       out   = (float*)d_out;           // 6*N*K floats
    radius_graph_kernel<<<N_ATOMS, SORT_N, 0, stream>>>(pos, batch, out);
}

// Round 2
// 79.499 us; speedup vs baseline: 1.1360x; 1.1360x over previous
//
#include <hip/hip_runtime.h>
#include <stdint.h>

#define N_ATOMS 8192
#define KNB 32            // MAX_NEIGHBORS
#define CUTOFF_F 5.0f
#define BLK 256           // >= max molecule size (observed safe in R1)

// One block per atom. batch sorted -> molecule = contiguous range (binary
// search, wave-uniform). Each thread computes one candidate's packed key
// (dist_bits<<32 | j); valid keys (dist <= cutoff) are compacted into LDS via
// ballot + one LDS atomic per wave. Then each compacted key's rank
// (= #{strictly smaller keys}) gives its output slot directly — exact
// jax.lax.top_k order (ascending dist, lower index first on ties) without a
// full sort. 2 barriers instead of 36; ~2C LDS broadcast reads (C ~ 40-100)
// instead of ~430 LDS ops/block.
__global__ __launch_bounds__(BLK) void radius_graph_kernel(
    const float* __restrict__ pos, const int* __restrict__ batch,
    float* __restrict__ out)
{
    const int i   = blockIdx.x;
    const int tid = threadIdx.x;
    __shared__ uint64_t list[BLK];
    __shared__ int s_cnt;
    if (tid == 0) s_cnt = 0;

    const int b = batch[i];

    // molecule range [start, end): wave-uniform binary searches
    int lo = 0, hi = N_ATOMS;
    while (lo < hi) { int mid = (lo + hi) >> 1; if (batch[mid] < b) lo = mid + 1; else hi = mid; }
    const int start = lo;
    lo = 0; hi = N_ATOMS;
    while (lo < hi) { int mid = (lo + hi) >> 1; if (batch[mid] <= b) lo = mid + 1; else hi = mid; }
    const int end = lo;

    const float xi = pos[3 * i], yi = pos[3 * i + 1], zi = pos[3 * i + 2];
    const float sqi = xi * xi + yi * yi + zi * zi;

    bool valid = false;
    uint64_t key = 0;
    const int j = start + tid;
    if (j < end && j != i) {
        const float xj = pos[3 * j], yj = pos[3 * j + 1], zj = pos[3 * j + 2];
        const float sqj = xj * xj + yj * yj + zj * zj;
        const float dot = xi * xj + yi * yj + zi * zj;
        const float d2  = (sqi + sqj) - 2.0f * dot;          // reference's gram trick
        const float dist = sqrtf(fmaxf(d2, 0.0f));
        if (dist <= CUTOFF_F) {
            valid = true;
            key = ((uint64_t)__float_as_uint(dist) << 32) | (uint32_t)j;
        }
    }
    __syncthreads();   // s_cnt init visible before atomics

    // per-wave compaction into LDS list
    const int lane = tid & 63;
    const unsigned long long m = __ballot(valid);
    const int prefix = __popcll(m & ((1ULL << lane) - 1ULL));
    int base = 0;
    if (lane == 0) base = atomicAdd(&s_cnt, __popcll(m));
    base = __shfl(base, 0);
    if (valid) list[base + prefix] = key;
    __syncthreads();

    const int C = s_cnt;                       // block-uniform valid count
    const long long NK = (long long)N_ATOMS * KNB;

    if (tid < C) {
        const uint64_t mykey = list[tid];
        int rank = 0;
        #pragma unroll 4
        for (int u = 0; u < C; ++u) rank += (list[u] < mykey) ? 1 : 0;   // broadcast reads
        if (rank < KNB) {
            const int dst = (int)(uint32_t)(mykey & 0xFFFFFFFFu);
            const long long e = (long long)i * KNB + rank;
            out[e]      = (float)i;
            out[NK + e] = (float)dst;
            out[2 * NK + 3 * e]     = pos[3 * dst]     - xi;
            out[2 * NK + 3 * e + 1] = pos[3 * dst + 1] - yi;
            out[2 * NK + 3 * e + 2] = pos[3 * dst + 2] - zi;
            out[5 * NK + e] = 1.0f;
        }
    } else if (tid < KNB) {                    // pad slots [C, 32): self-edges
        const long long e = (long long)i * KNB + tid;
        out[e]      = (float)i;
        out[NK + e] = (float)i;
        out[2 * NK + 3 * e]     = 0.0f;
        out[2 * NK + 3 * e + 1] = 0.0f;
        out[2 * NK + 3 * e + 2] = 0.0f;
        out[5 * NK + e] = 0.0f;
    }
}

extern "C" void kernel_launch(void* const* d_in, const int* in_sizes, int n_in,
                              void* d_out, int out_size, void* d_ws, size_t ws_size,
                              hipStream_t stream) {
    const float* pos   = (const float*)d_in[0];   // [8192, 3] f32
    const int*   batch = (const int*)d_in[1];     // [8192] i32, sorted
    float*       out   = (float*)d_out;           // 6*N*K floats
    radius_graph_kernel<<<N_ATOMS, BLK, 0, stream>>>(pos, batch, out);
}

// Round 3
// 65.440 us; speedup vs baseline: 1.3801x; 1.2148x over previous
//
#include <hip/hip_runtime.h>
#include <stdint.h>

#define N_ATOMS 8192
#define KNB 32            // MAX_NEIGHBORS
#define CUTOFF_F 5.0f
#define N_MOLS 64
#define CAP 256           // max supported molecule size (Binomial(8192,1/64): P(>195) ~ 1e-7; validated R1/R2)

// Kernel 1: molecule ranges via boundary detection on the sorted batch array.
// ranges[2m] = first index of molecule m, ranges[2m+1] = one-past-last.
// Fully parallel O(N) — replaces 26 dependent binary-search loads per atom-block.
__global__ void mol_ranges_kernel(const int* __restrict__ batch, int* __restrict__ ranges) {
    const int k = blockIdx.x * blockDim.x + threadIdx.x;
    if (k >= N_ATOMS) return;
    const int v = batch[k];
    if (k == 0) {
        ranges[2 * v] = 0;
    } else {
        const int w = batch[k - 1];
        if (w != v) { ranges[2 * w + 1] = k; ranges[2 * v] = k; }
    }
    if (k == N_ATOMS - 1) ranges[2 * v + 1] = N_ATOMS;
}

// Kernel 2: one 64-thread wave per atom. Each lane covers up to 4 candidates
// (j = start + lane + 64q, uniform early-exit on q). Valid keys
// (dist_bits<<32 | j) are wave-compacted into LDS; each key's rank
// (#{strictly smaller}) is its output slot — exact jax.lax.top_k order.
// Winners land in a 32-slot LDS array (default self) so lanes 0..31 do one
// coalesced write pass; pads produce vec==0 naturally (pos[i]-pos[i]).
__global__ __launch_bounds__(64) void radius_graph_kernel(
    const float* __restrict__ pos, const int* __restrict__ batch,
    const int* __restrict__ ranges, float* __restrict__ out)
{
    const int i    = blockIdx.x;
    const int lane = threadIdx.x;
    __shared__ uint64_t list[CAP];
    __shared__ int win[KNB];

    const int b     = batch[i];        // uniform -> scalar loads
    const int start = ranges[2 * b];
    const int end   = ranges[2 * b + 1];

    const float xi = pos[3 * i], yi = pos[3 * i + 1], zi = pos[3 * i + 2];
    const float sqi = xi * xi + yi * yi + zi * zi;

    int cnt = 0;                       // wave-uniform valid count (scalar)
    #pragma unroll
    for (int q = 0; q < 4; ++q) {
        const int jbase = start + (q << 6);
        if (jbase >= end) break;       // uniform exit: most molecules need q<2
        const int j = jbase + lane;
        bool valid = false; uint64_t key = 0;
        if (j < end && j != i) {
            const float xj = pos[3 * j], yj = pos[3 * j + 1], zj = pos[3 * j + 2];
            const float sqj = xj * xj + yj * yj + zj * zj;
            const float dot = xi * xj + yi * yj + zi * zj;
            const float d2  = (sqi + sqj) - 2.0f * dot;     // reference's gram trick
            const float dist = sqrtf(fmaxf(d2, 0.0f));
            if (dist <= CUTOFF_F) {
                valid = true;
                key = ((uint64_t)__float_as_uint(dist) << 32) | (uint32_t)j;
            }
        }
        const unsigned long long m = __ballot(valid);
        if (valid)
            list[cnt + __popcll(m & ((1ULL << lane) - 1ULL))] = key;
        cnt += __popcll(m);
    }

    if (lane < KNB) win[lane] = i;     // default pad: self-edge
    __syncthreads();                   // 64-thread wg: compiles to waitcnt (+trivial barrier)

    const int C = cnt;
    for (int t = lane; t < C; t += 64) {
        const uint64_t my = list[t];
        int r = 0;
        #pragma unroll 4
        for (int u = 0; u < C; ++u) r += (list[u] < my) ? 1 : 0;   // broadcast reads
        if (r < KNB) win[r] = (int)(uint32_t)(my & 0xFFFFFFFFu);
    }
    __syncthreads();

    if (lane < KNB) {
        const int dst = win[lane];
        const long long NK = (long long)N_ATOMS * KNB;
        const long long e  = (long long)i * KNB + lane;
        out[e]      = (float)i;
        out[NK + e] = (float)dst;
        // real edge: pos[dst]-pos[i]; pad: dst==i -> exactly 0.0
        out[2 * NK + 3 * e]     = pos[3 * dst]     - xi;
        out[2 * NK + 3 * e + 1] = pos[3 * dst + 1] - yi;
        out[2 * NK + 3 * e + 2] = pos[3 * dst + 2] - zi;
        out[5 * NK + e] = (lane < C) ? 1.0f : 0.0f;
    }
}

extern "C" void kernel_launch(void* const* d_in, const int* in_sizes, int n_in,
                              void* d_out, int out_size, void* d_ws, size_t ws_size,
                              hipStream_t stream) {
    const float* pos   = (const float*)d_in[0];   // [8192, 3] f32
    const int*   batch = (const int*)d_in[1];     // [8192] i32, sorted
    float*       out   = (float*)d_out;           // 6*N*K floats
    int*         ranges = (int*)d_ws;             // [2*N_MOLS] ints

    mol_ranges_kernel<<<(N_ATOMS + 255) / 256, 256, 0, stream>>>(batch, ranges);
    radius_graph_kernel<<<N_ATOMS, 64, 0, stream>>>(pos, batch, ranges, out);
}